// Round 3
// baseline (364.934 us; speedup 1.0000x reference)
//
#include <hip/hip_runtime.h>
#include <hip/hip_bf16.h>
#include <stdint.h>
#include <stddef.h>

// Problem constants (fixed by the reference)
#define B_ 4
#define N_ 2048
#define E_ 1024
#define H_ 16
#define D_ 64
// SCALE = 1/sqrt(64) = 0.125 exactly (applied by pre-scaling Q, exact in bf16)
// All reference tensors are float32; internally bf16 for MFMA.

using bf16 = __hip_bfloat16;
typedef __bf16 bf16x8 __attribute__((ext_vector_type(8)));   // 4 VGPRs, MFMA A/B frag
typedef float  f32x4  __attribute__((ext_vector_type(4)));   // MFMA C/D frag (16x16)
typedef float  f32x16 __attribute__((ext_vector_type(16)));  // MFMA C/D frag (32x32)
typedef unsigned int u32x2 __attribute__((ext_vector_type(2)));

// ---- dtype helpers --------------------------------------------------------
__device__ inline bf16x8 load8(const float* p) {
    f32x4 a = *(const f32x4*)p;
    f32x4 b = *(const f32x4*)(p + 4);
    bf16x8 r;
#pragma unroll
    for (int e = 0; e < 4; e++) { r[e] = (__bf16)a[e]; r[e + 4] = (__bf16)b[e]; }
    return r;
}
__device__ inline void store_elem(float* C, size_t idx, float v) { C[idx] = v; }
__device__ inline void store_elem(bf16* C, size_t idx, float v) {
    C[idx] = __float2bfloat16(v);
}

// Async global->LDS, 16 B per lane (LDS dest = wave-uniform base + lane*16).
__device__ inline void async_stage16(const bf16* g, bf16* l) {
    __builtin_amdgcn_global_load_lds(
        (const __attribute__((address_space(1))) uint32_t*)g,
        (__attribute__((address_space(3))) uint32_t*)l, 16, 0, 0);
}
__device__ inline void manual_stage16(const float* g, bf16* l) {
    *(bf16x8*)l = load8(g);
}

// LDS-only barrier: orders LDS ops (lgkmcnt) + execution sync, but does NOT
// drain vmcnt -- in-flight global loads (register destinations, wave-private)
// ride across it. __syncthreads() would emit s_waitcnt vmcnt(0) and eat the
// full global-load latency every tile. All ds ops here are compiler-emitted,
// so the compiler still inserts its own counted lgkm/vm waits for real deps.
__device__ inline void lds_barrier() {
    asm volatile("s_waitcnt lgkmcnt(0)" ::: "memory");
    __builtin_amdgcn_s_barrier();
}

// ---------------------------------------------------------------------------
// fp32 -> bf16 convert. Blocks 0..2047: weights (512 each); blocks
// 2048..14335: the 3 inputs (4096 each).
// ---------------------------------------------------------------------------
__global__ __launch_bounds__(256) void cvt_all(
    const float* __restrict__ w0, const float* __restrict__ w1,
    const float* __restrict__ w2, const float* __restrict__ w3,
    bf16* __restrict__ wd,
    const float* __restrict__ x0, const float* __restrict__ x1,
    const float* __restrict__ x2,
    bf16* __restrict__ xd0, bf16* __restrict__ xd1, bf16* __restrict__ xd2)
{
    int bx = blockIdx.x;
    const float* s; bf16* d;
    if (bx < 2048) {
        const int seg = bx >> 9;
        s = seg == 0 ? w0 : seg == 1 ? w1 : seg == 2 ? w2 : w3;
        d = wd + (size_t)seg * (E_ * E_);
        bx &= 511;
    } else {
        bx -= 2048;
        const int seg = bx >> 12;
        s = seg == 0 ? x0 : seg == 1 ? x1 : x2;
        d = seg == 0 ? xd0 : seg == 1 ? xd1 : xd2;
        bx &= 4095;
    }
    const size_t off = ((size_t)bx * 256 + threadIdx.x) * 8;
    *(bf16x8*)&d[off] = load8(s + off);
}

// ---------------------------------------------------------------------------
// GEMM: C[M,E] = A[M,E] @ W[E,E]^T (+ optional fp32 bias), fp32 accumulate,
// v_mfma_f32_16x16x32_bf16, 128x128 tile, BK=32, 4 waves; batched blockIdx.z.
// bf16 path: both operands via async global_load_lds width=16 (m97).
// ---------------------------------------------------------------------------
struct GemmB { const void* A[3]; void* C[3]; };

template <typename TA, typename TC>
__global__ __launch_bounds__(256) void gemm_bt(
    GemmB batch, const bf16* __restrict__ Wb, const float* __restrict__ bias)
{
    __shared__ bf16 As[128 * 32];
    __shared__ bf16 Bs[128 * 32];

    const TA*   __restrict__ A = (const TA*)batch.A[blockIdx.z];
    TC*         __restrict__ C = (TC*)batch.C[blockIdx.z];
    const bf16* __restrict__ W = Wb + (size_t)blockIdx.z * (E_ * E_);

    const int tid  = threadIdx.x;
    const int lane = tid & 63;
    const int wave = tid >> 6;
    const int wr   = wave >> 1;
    const int wc   = wave & 1;
    const int r    = lane & 15;
    const int quad = lane >> 4;

    const int m0 = blockIdx.y * 128;
    const int n0 = blockIdx.x * 128;

    const int row0 = tid >> 2,         cc0 = (tid & 3) * 8;
    const int row1 = (tid + 256) >> 2, cc1 = cc0;

    f32x4 acc[4][4];
#pragma unroll
    for (int i = 0; i < 4; i++)
#pragma unroll
        for (int j = 0; j < 4; j++)
            acc[i][j] = {0.0f, 0.0f, 0.0f, 0.0f};

    for (int k0 = 0; k0 < E_; k0 += 32) {
        __syncthreads();
        if constexpr (__is_same(TA, bf16)) {
            async_stage16(&A[(size_t)(m0 + row0) * E_ + k0 + cc0], &As[tid * 8]);
            async_stage16(&A[(size_t)(m0 + row1) * E_ + k0 + cc1], &As[(tid + 256) * 8]);
        } else {
            manual_stage16(&A[(size_t)(m0 + row0) * E_ + k0 + cc0], &As[tid * 8]);
            manual_stage16(&A[(size_t)(m0 + row1) * E_ + k0 + cc1], &As[(tid + 256) * 8]);
        }
        async_stage16(&W[(size_t)(n0 + row0) * E_ + k0 + cc0], &Bs[tid * 8]);
        async_stage16(&W[(size_t)(n0 + row1) * E_ + k0 + cc1], &Bs[(tid + 256) * 8]);
        __syncthreads();

        bf16x8 a[4], b[4];
#pragma unroll
        for (int mt = 0; mt < 4; mt++)
            a[mt] = *(const bf16x8*)&As[(wr * 64 + mt * 16 + r) * 32 + quad * 8];
#pragma unroll
        for (int nt = 0; nt < 4; nt++)
            b[nt] = *(const bf16x8*)&Bs[(wc * 64 + nt * 16 + r) * 32 + quad * 8];
#pragma unroll
        for (int mt = 0; mt < 4; mt++)
#pragma unroll
            for (int nt = 0; nt < 4; nt++)
                acc[mt][nt] = __builtin_amdgcn_mfma_f32_16x16x32_bf16(
                    a[mt], b[nt], acc[mt][nt], 0, 0, 0);
    }

#pragma unroll
    for (int mt = 0; mt < 4; mt++) {
#pragma unroll
        for (int nt = 0; nt < 4; nt++) {
            const int col = n0 + wc * 64 + nt * 16 + r;
            float bv = bias ? bias[col] : 0.0f;
#pragma unroll
            for (int rg = 0; rg < 4; rg++) {
                const int row = m0 + wr * 64 + mt * 16 + quad * 4 + rg;
                store_elem(C, (size_t)row * E_ + col, acc[mt][nt][rg] + bv);
            }
        }
    }
}

// ---------------------------------------------------------------------------
// MFMA flash attention, round-9.
//
// Round-8 result: identical 102.7us despite removing bank conflicts + VALU
// work -> bottleneck invariant = the {barrier-drain, depth-1 prefetch}
// skeleton. __syncthreads() drains vmcnt(0) on loads issued THIS tile whose
// consumer is NEXT tile's commit -> every tile pays the congested global-load
// round trip; all 8 waves/CU in lockstep, ~75% of T_tile is stall.
//
// Round-9 (one coherent change): decouple load latency from the barrier.
//  (1) lds_barrier(): s_waitcnt lgkmcnt(0) + s_barrier only. LDS hazards
//      (buffer reuse) are fully covered; global loads target registers
//      (wave-private) and legally stay in flight across the barrier.
//  (2) 2-deep register prefetch: two named sets (even/odd tiles, statically
//      indexed). Commit of tile t+1 waits only the older set (vmcnt(4)),
//      with ~2 tile-iterations of slack.
// Everything else unchanged from round-8 (32x32x16 S^T/PV, in-register P via
// cvt_pk+permlane32_swap, defer-max THR=8, exp2 domain, balanced strip pairs).
// ---------------------------------------------------------------------------
__global__ __launch_bounds__(256) void attn_fwd(
    const bf16* __restrict__ q, const bf16* __restrict__ k,
    const bf16* __restrict__ v, bf16* __restrict__ o)
{
    constexpr int LS = 72;
    constexpr float LOG2E = 1.44269504088896340736f;
    __shared__ bf16 Ks[2][64 * LS];   // [buf][key][d]
    __shared__ bf16 Vt[2][64 * LS];   // [buf][d][key]

    const int tid  = threadIdx.x;
    const int lane = tid & 63;
    const int wave = tid >> 6;
    const int l31  = lane & 31;
    const int hi   = lane >> 5;

    const int bh = blockIdx.y;
    const int b  = bh >> 4;
    const int h  = bh & 15;
    const int p  = blockIdx.x;        // 0..7

    const size_t basek = (size_t)b * N_ * E_ + (size_t)h * D_;

    // staging addressing
    const int key0 = tid >> 3;        // 0..31
    const int key1 = key0 + 32;
    const int ck   = (tid & 7) * 8;
    const int kp   = tid & 31;
    const int cv   = (tid >> 5) * 8;

    // load a K/V tile j into a register set
    auto LOADSET = [&](bf16x8& a0, bf16x8& a1, bf16x8& a2, bf16x8& a3, int j) {
        const size_t jb = (size_t)j * 64;
        a0 = *(const bf16x8*)&k[basek + (jb + key0) * E_ + ck];
        a1 = *(const bf16x8*)&k[basek + (jb + key1) * E_ + ck];
        a2 = *(const bf16x8*)&v[basek + (jb + 2 * kp) * E_ + cv];
        a3 = *(const bf16x8*)&v[basek + (jb + 2 * kp + 1) * E_ + cv];
    };
    // commit a register set to LDS buffer buf
    auto COMMIT = [&](const bf16x8& a0, const bf16x8& a1,
                      const bf16x8& a2, const bf16x8& a3, int buf) {
        *(bf16x8*)&Ks[buf][key0 * LS + ck] = a0;
        *(bf16x8*)&Ks[buf][key1 * LS + ck] = a1;
#pragma unroll
        for (int e = 0; e < 8; e++) {
            union { __bf16 hh[2]; uint32_t u; } pk;
            pk.hh[0] = a2[e]; pk.hh[1] = a3[e];
            *(uint32_t*)&Vt[buf][(cv + e) * LS + 2 * kp] = pk.u;
        }
    };

#pragma unroll
    for (int ph = 0; ph < 2; ph++) {
        const int xb = ph == 0 ? (15 - p) : p;
        const int q0 = xb * 128;
        const int nt = 2 * xb + 2;    // key tiles 0..nt-1 (keys 0..q0+127)

        // Q as B-operand of 32x32x16: B[k=hi*8+e][col=qrow=l31], kc selects
        // which 16 of D=64. Pre-scaled by 0.125 (exact in bf16).
        bf16x8 qB[4];
        {
            const size_t qoff =
                ((size_t)b * N_ + q0 + wave * 32 + l31) * E_ + h * D_ + hi * 8;
#pragma unroll
            for (int kc = 0; kc < 4; kc++) {
                qB[kc] = *(const bf16x8*)&q[qoff + kc * 16];
#pragma unroll
                for (int e = 0; e < 8; e++)
                    qB[kc][e] = (__bf16)((float)qB[kc][e] * 0.125f);
            }
        }

        float m_i = -1e30f;
        float l_i = 0.0f;
        f32x16 o_acc[2];              // O^T C-layout: col=qrow, row=d half
#pragma unroll
        for (int rg = 0; rg < 16; rg++) { o_acc[0][rg] = 0.0f; o_acc[1][rg] = 0.0f; }

        // ---- prologue ----
        // set0 holds even tiles (0,2,4,..), set1 odd tiles (1,3,5,..)
        bf16x8 s0k0, s0k1, s0v0, s0v1;   // even set
        bf16x8 s1k0, s1k1, s1v0, s1v1;   // odd set
        LOADSET(s0k0, s0k1, s0v0, s0v1, 0);
        // (prior phase ended with a barrier -> buffers free)
        COMMIT(s0k0, s0k1, s0v0, s0v1, 0);   // vmcnt drain once per phase
        LOADSET(s1k0, s1k1, s1v0, s1v1, 1);  // nt >= 2 always
        if (2 < nt) LOADSET(s0k0, s0k1, s0v0, s0v1, 2);
        lds_barrier();                // buf0 visible to all waves

        for (int t = 0; t < nt; t++) {
            const int cur = t & 1;

            // ---- commit tile t+1 (older prefetch set) to buf[cur^1];
            //      compiler waits vmcnt(4) (only the newer set outstanding).
            //      Then reload that set with tile t+3 (same parity). ----
            if (cur == 0) {
                if (t + 1 < nt) COMMIT(s1k0, s1k1, s1v0, s1v1, 1);
                if (t + 3 < nt) LOADSET(s1k0, s1k1, s1v0, s1v1, t + 3);
            } else {
                if (t + 1 < nt) COMMIT(s0k0, s0k1, s0v0, s0v1, 0);
                if (t + 3 < nt) LOADSET(s0k0, s0k1, s0v0, s0v1, t + 3);
            }

            // ---- S^T[key][qrow] = K·(scaled Q)^T : 8 MFMA 32x32x16 ----
            f32x16 sf[2];
#pragma unroll
            for (int rg = 0; rg < 16; rg++) { sf[0][rg] = 0.0f; sf[1][rg] = 0.0f; }
#pragma unroll
            for (int kc = 0; kc < 4; kc++) {
                bf16x8 ka0 = *(const bf16x8*)&Ks[cur][l31 * LS + kc * 16 + hi * 8];
                bf16x8 ka1 = *(const bf16x8*)&Ks[cur][(32 + l31) * LS + kc * 16 + hi * 8];
                sf[0] = __builtin_amdgcn_mfma_f32_32x32x16_bf16(ka0, qB[kc], sf[0], 0, 0, 0);
                sf[1] = __builtin_amdgcn_mfma_f32_32x32x16_bf16(ka1, qB[kc], sf[1], 0, 0, 0);
            }

            // ---- causal mask (only last 2 tiles of the phase) ----
            // key = mt*32 + (rg&3) + 8*(rg>>2) + 4*hi ; qrow = l31
            if (t >= nt - 2) {
                const int qgl   = q0 + wave * 32 + l31;
                const int kbase = t * 64 + 4 * hi;
#pragma unroll
                for (int mt = 0; mt < 2; mt++)
#pragma unroll
                    for (int rg = 0; rg < 16; rg++) {
                        const int kgl = kbase + mt * 32 + (rg & 3) + 8 * (rg >> 2);
                        if (kgl > qgl) sf[mt][rg] = -1e30f;
                    }
            }

            // ---- online softmax: each lane owns half its q-row; partner
            //      lane (l^32) owns the other half ----
            float mhalf[8];
#pragma unroll
            for (int i = 0; i < 8; i++)
                mhalf[i] = fmaxf(fmaxf(sf[0][2 * i], sf[0][2 * i + 1]),
                                 fmaxf(sf[1][2 * i], sf[1][2 * i + 1]));
            float mx = fmaxf(fmaxf(fmaxf(mhalf[0], mhalf[1]), fmaxf(mhalf[2], mhalf[3])),
                             fmaxf(fmaxf(mhalf[4], mhalf[5]), fmaxf(mhalf[6], mhalf[7])));
            mx = fmaxf(mx, __shfl_xor(mx, 32));

            // defer-max (THR=8): rescale only when the running max really grew
            if (!__all(mx <= m_i + 8.0f)) {
                const float m_new = fmaxf(m_i, mx);
                const float al = exp2f((m_i - m_new) * LOG2E);
                l_i *= al;
#pragma unroll
                for (int mo = 0; mo < 2; mo++)
#pragma unroll
                    for (int rg = 0; rg < 16; rg++) o_acc[mo][rg] *= al;
                m_i = m_new;
            }

            const float m2 = m_i * LOG2E;
#pragma unroll
            for (int mt = 0; mt < 2; mt++)
#pragma unroll
                for (int rg = 0; rg < 16; rg++)
                    sf[mt][rg] = exp2f(__builtin_fmaf(sf[mt][rg], LOG2E, -m2));

            float ls = 0.0f;
#pragma unroll
            for (int mt = 0; mt < 2; mt++) {
                const float a0 = (sf[mt][0] + sf[mt][1]) + (sf[mt][2] + sf[mt][3]);
                const float a1 = (sf[mt][4] + sf[mt][5]) + (sf[mt][6] + sf[mt][7]);
                const float a2 = (sf[mt][8] + sf[mt][9]) + (sf[mt][10] + sf[mt][11]);
                const float a3 = (sf[mt][12] + sf[mt][13]) + (sf[mt][14] + sf[mt][15]);
                ls += (a0 + a1) + (a2 + a3);
            }
            ls += __shfl_xor(ls, 32);
            l_i += ls;

            // ---- pack P to bf16 pair-words (v_cvt_pk_bf16_f32) ----
            uint32_t w[2][8];
#pragma unroll
            for (int mt = 0; mt < 2; mt++)
#pragma unroll
                for (int i = 0; i < 8; i++) {
                    union { __bf16 hh[2]; uint32_t u; } pk;
                    pk.hh[0] = (__bf16)sf[mt][2 * i];
                    pk.hh[1] = (__bf16)sf[mt][2 * i + 1];
                    w[mt][i] = pk.u;
                }

            // ---- O^T += V^T · P^T : PV B-frags via permlane32_swap ----
            // r1 = swap(w[c], w[c+2]) -> m0 = r1[0], m2 = r1[1] (both halves)
            // r2 = swap(w[c+1], w[c+3]) -> m1 = r2[0], m3 = r2[1]
#pragma unroll
            for (int ks = 0; ks < 4; ks++) {
                const int c  = 4 * (ks & 1);
                const int mt = ks >> 1;
                u32x2 r1 = __builtin_amdgcn_permlane32_swap(
                    w[mt][c + 0], w[mt][c + 2], false, false);
                u32x2 r2 = __builtin_amdgcn_permlane32_swap(
                    w[mt][c + 1], w[mt][c + 3], false, false);
                union { uint32_t u[4]; bf16x8 v8; } pbu;
                pbu.u[0] = r1[0]; pbu.u[1] = r2[0];
                pbu.u[2] = r1[1]; pbu.u[3] = r2[1];
#pragma unroll
                for (int mo = 0; mo < 2; mo++) {
                    bf16x8 va = *(const bf16x8*)
                        &Vt[cur][(mo * 32 + l31) * LS + ks * 16 + hi * 8];
                    o_acc[mo] = __builtin_amdgcn_mfma_f32_32x32x16_bf16(
                        va, pbu.v8, o_acc[mo], 0, 0, 0);
                }
            }

            lds_barrier();   // buf[cur] free for next commit; buf[cur^1] visible
        }

        // ---- normalize + store (O^T: col=qrow=l31, row=d) ----
        {
            const float invl = 1.0f / l_i;
            const size_t orow =
                ((size_t)b * N_ + q0 + wave * 32 + l31) * E_ + h * D_;
#pragma unroll
            for (int mo = 0; mo < 2; mo++)
#pragma unroll
                for (int g = 0; g < 4; g++) {
                    union { __bf16 hh[4]; uint2 u2; } pk;
#pragma unroll
                    for (int j = 0; j < 4; j++)
                        pk.hh[j] = (__bf16)(o_acc[mo][4 * g + j] * invl);
                    *(uint2*)&o[orow + mo * 32 + 8 * g + 4 * hi] = pk.u2;
                }
        }
    }
}

// ---------------------------------------------------------------------------
// Inputs: xq, xk, xv, attn_mask, Wq, Wk, Wv, Wo, bo (all fp32; mask structural)
// ws (big): q|k|v|ao (bf16 8.4M each) | Wb (4x1M) | xb0..2 (8.4M each) =126 MB
// ws (small fallback): first 75.5 MB only; proj GEMM stages fp32 A manually.
// ---------------------------------------------------------------------------
extern "C" void kernel_launch(void* const* d_in, const int* in_sizes, int n_in,
                              void* d_out, int out_size, void* d_ws, size_t ws_size,
                              hipStream_t stream) {
    const float* xq = (const float*)d_in[0];
    const float* xk = (const float*)d_in[1];
    const float* xv = (const float*)d_in[2];
    const float* Wq = (const float*)d_in[4];
    const float* Wk = (const float*)d_in[5];
    const float* Wv = (const float*)d_in[6];
    const float* Wo = (const float*)d_in[7];
    const float* bo = (const float*)d_in[8];
    float* out = (float*)d_out;

    const size_t elems = (size_t)B_ * N_ * E_;   // 8388608
    const size_t wel   = (size_t)E_ * E_;        // 1048576
    bf16* q   = (bf16*)d_ws;
    bf16* kk  = q + elems;
    bf16* vv  = kk + elems;
    bf16* ao  = vv + elems;
    bf16* Wb  = ao + elems;
    bf16* xb0 = Wb + 4 * wel;
    bf16* xb1 = xb0 + elems;
    bf16* xb2 = xb1 + elems;

    const size_t need_big = (7 * elems + 4 * wel) * 2;
    const bool big = ws_size >= need_big;

    dim3 blk(256);
    if (big) {
        cvt_all<<<dim3(14336), blk, 0, stream>>>(
            Wq, Wk, Wv, Wo, Wb, xq, xk, xv, xb0, xb1, xb2);
    } else {
        cvt_all<<<dim3(2048), blk, 0, stream>>>(
            Wq, Wk, Wv, Wo, Wb, nullptr, nullptr, nullptr,
            nullptr, nullptr, nullptr);
    }

    GemmB proj;
    if (big) { proj.A[0] = xb0; proj.A[1] = xb1; proj.A[2] = xb2; }
    else     { proj.A[0] = xq;  proj.A[1] = xk;  proj.A[2] = xv;  }
    proj.C[0] = q; proj.C[1] = kk; proj.C[2] = vv;
    if (big)
        gemm_bt<bf16, bf16><<<dim3(E_ / 128, (B_ * N_) / 128, 3), blk, 0, stream>>>(
            proj, Wb, nullptr);
    else
        gemm_bt<float, bf16><<<dim3(E_ / 128, (B_ * N_) / 128, 3), blk, 0, stream>>>(
            proj, Wb, nullptr);

    attn_fwd<<<dim3(8, B_ * H_), blk, 0, stream>>>(q, kk, vv, ao);

    GemmB fin;
    fin.A[0] = ao; fin.A[1] = ao; fin.A[2] = ao;
    fin.C[0] = out; fin.C[1] = out; fin.C[2] = out;
    gemm_bt<bf16, float><<<dim3(E_ / 128, (B_ * N_) / 128, 1), blk, 0, stream>>>(
        fin, Wb + 3 * wel, bo);
}

// Round 4
// 345.038 us; speedup vs baseline: 1.0577x; 1.0577x over previous
//
#include <hip/hip_runtime.h>
#include <hip/hip_bf16.h>
#include <stdint.h>
#include <stddef.h>

// Problem constants (fixed by the reference)
#define B_ 4
#define N_ 2048
#define E_ 1024
#define H_ 16
#define D_ 64
// SCALE = 1/sqrt(64) = 0.125 exactly (applied by pre-scaling Q, exact in bf16)
// All reference tensors are float32; internally bf16 for MFMA.

using bf16 = __hip_bfloat16;
typedef __bf16 bf16x8 __attribute__((ext_vector_type(8)));   // 4 VGPRs, MFMA A/B frag
typedef float  f32x4  __attribute__((ext_vector_type(4)));   // MFMA C/D frag (16x16)
typedef float  f32x16 __attribute__((ext_vector_type(16)));  // MFMA C/D frag (32x32)
typedef unsigned int u32x2 __attribute__((ext_vector_type(2)));

// ---- dtype helpers --------------------------------------------------------
__device__ inline bf16x8 load8(const float* p) {
    f32x4 a = *(const f32x4*)p;
    f32x4 b = *(const f32x4*)(p + 4);
    bf16x8 r;
#pragma unroll
    for (int e = 0; e < 4; e++) { r[e] = (__bf16)a[e]; r[e + 4] = (__bf16)b[e]; }
    return r;
}
__device__ inline void store_elem(float* C, size_t idx, float v) { C[idx] = v; }
__device__ inline void store_elem(bf16* C, size_t idx, float v) {
    C[idx] = __float2bfloat16(v);
}

// Async global->LDS, 16 B per lane (LDS dest = wave-uniform base + lane*16).
__device__ inline void async_stage16(const bf16* g, bf16* l) {
    __builtin_amdgcn_global_load_lds(
        (const __attribute__((address_space(1))) uint32_t*)g,
        (__attribute__((address_space(3))) uint32_t*)l, 16, 0, 0);
}
__device__ inline void manual_stage16(const float* g, bf16* l) {
    *(bf16x8*)l = load8(g);
}

// ---------------------------------------------------------------------------
// fp32 -> bf16 convert. Blocks 0..2047: weights (512 each); blocks
// 2048..14335: the 3 inputs (4096 each).
// ---------------------------------------------------------------------------
__global__ __launch_bounds__(256) void cvt_all(
    const float* __restrict__ w0, const float* __restrict__ w1,
    const float* __restrict__ w2, const float* __restrict__ w3,
    bf16* __restrict__ wd,
    const float* __restrict__ x0, const float* __restrict__ x1,
    const float* __restrict__ x2,
    bf16* __restrict__ xd0, bf16* __restrict__ xd1, bf16* __restrict__ xd2)
{
    int bx = blockIdx.x;
    const float* s; bf16* d;
    if (bx < 2048) {
        const int seg = bx >> 9;
        s = seg == 0 ? w0 : seg == 1 ? w1 : seg == 2 ? w2 : w3;
        d = wd + (size_t)seg * (E_ * E_);
        bx &= 511;
    } else {
        bx -= 2048;
        const int seg = bx >> 12;
        s = seg == 0 ? x0 : seg == 1 ? x1 : x2;
        d = seg == 0 ? xd0 : seg == 1 ? xd1 : xd2;
        bx &= 4095;
    }
    const size_t off = ((size_t)bx * 256 + threadIdx.x) * 8;
    *(bf16x8*)&d[off] = load8(s + off);
}

// ---------------------------------------------------------------------------
// GEMM: C[M,E] = A[M,E] @ W[E,E]^T (+ optional fp32 bias), fp32 accumulate,
// v_mfma_f32_16x16x32_bf16, 128x128 tile, BK=32, 4 waves; batched blockIdx.z.
// bf16 path: both operands via async global_load_lds width=16 (m97).
// ---------------------------------------------------------------------------
struct GemmB { const void* A[3]; void* C[3]; };

template <typename TA, typename TC>
__global__ __launch_bounds__(256) void gemm_bt(
    GemmB batch, const bf16* __restrict__ Wb, const float* __restrict__ bias)
{
    __shared__ bf16 As[128 * 32];
    __shared__ bf16 Bs[128 * 32];

    const TA*   __restrict__ A = (const TA*)batch.A[blockIdx.z];
    TC*         __restrict__ C = (TC*)batch.C[blockIdx.z];
    const bf16* __restrict__ W = Wb + (size_t)blockIdx.z * (E_ * E_);

    const int tid  = threadIdx.x;
    const int lane = tid & 63;
    const int wave = tid >> 6;
    const int wr   = wave >> 1;
    const int wc   = wave & 1;
    const int r    = lane & 15;
    const int quad = lane >> 4;

    const int m0 = blockIdx.y * 128;
    const int n0 = blockIdx.x * 128;

    const int row0 = tid >> 2,         cc0 = (tid & 3) * 8;
    const int row1 = (tid + 256) >> 2, cc1 = cc0;

    f32x4 acc[4][4];
#pragma unroll
    for (int i = 0; i < 4; i++)
#pragma unroll
        for (int j = 0; j < 4; j++)
            acc[i][j] = {0.0f, 0.0f, 0.0f, 0.0f};

    for (int k0 = 0; k0 < E_; k0 += 32) {
        __syncthreads();
        if constexpr (__is_same(TA, bf16)) {
            async_stage16(&A[(size_t)(m0 + row0) * E_ + k0 + cc0], &As[tid * 8]);
            async_stage16(&A[(size_t)(m0 + row1) * E_ + k0 + cc1], &As[(tid + 256) * 8]);
        } else {
            manual_stage16(&A[(size_t)(m0 + row0) * E_ + k0 + cc0], &As[tid * 8]);
            manual_stage16(&A[(size_t)(m0 + row1) * E_ + k0 + cc1], &As[(tid + 256) * 8]);
        }
        async_stage16(&W[(size_t)(n0 + row0) * E_ + k0 + cc0], &Bs[tid * 8]);
        async_stage16(&W[(size_t)(n0 + row1) * E_ + k0 + cc1], &Bs[(tid + 256) * 8]);
        __syncthreads();

        bf16x8 a[4], b[4];
#pragma unroll
        for (int mt = 0; mt < 4; mt++)
            a[mt] = *(const bf16x8*)&As[(wr * 64 + mt * 16 + r) * 32 + quad * 8];
#pragma unroll
        for (int nt = 0; nt < 4; nt++)
            b[nt] = *(const bf16x8*)&Bs[(wc * 64 + nt * 16 + r) * 32 + quad * 8];
#pragma unroll
        for (int mt = 0; mt < 4; mt++)
#pragma unroll
            for (int nt = 0; nt < 4; nt++)
                acc[mt][nt] = __builtin_amdgcn_mfma_f32_16x16x32_bf16(
                    a[mt], b[nt], acc[mt][nt], 0, 0, 0);
    }

#pragma unroll
    for (int mt = 0; mt < 4; mt++) {
#pragma unroll
        for (int nt = 0; nt < 4; nt++) {
            const int col = n0 + wc * 64 + nt * 16 + r;
            float bv = bias ? bias[col] : 0.0f;
#pragma unroll
            for (int rg = 0; rg < 4; rg++) {
                const int row = m0 + wr * 64 + mt * 16 + quad * 4 + rg;
                store_elem(C, (size_t)row * E_ + col, acc[mt][nt][rg] + bv);
            }
        }
    }
}

// ---------------------------------------------------------------------------
// MFMA flash attention, round-10 (= round-8 body + XCD-locality swizzle).
//
// Evidence trail: rounds 6 and 8 identical (102.7us) despite totally
// different VALU/LDS inner loops; round 9 (barrier/prefetch restructure)
// regressed 14% -> no CU pipe and no barrier drain is the wall. The match:
// K/V stream = 512 blocks x 34 tiles x 16KB = 278 MB per dispatch at
// 2.7 TB/s == T_tile. FETCH_SIZE 147.5 MB vs 33.5 MB distinct K/V = 4.4x
// over-fetch: grid (8,64) put the 8 blocks of each bh (which read NESTED
// key ranges, 8.5x re-read) on 8 DIFFERENT XCDs (XCD = linear%8 = p), so
// every re-read missed the 4MB per-XCD L2 (per-XCD working set 32MB).
//
// Round-10: 1-D grid 512, work swizzled so all 8 blocks of a bh share one
// XCD (l % 8 == bh % 8 under the round-robin dispatch model that also
// explains round-5's imbalance): bh's K/V = 512KB fits L2, re-reads become
// L2 hits; the 2 same-CU blocks also share bh (L1 reuse). Work perfectly
// balanced (34 tiles/block). Inner loop is round-8 verbatim (32x32x16
// S^T/PV, in-register P via cvt_pk+permlane32_swap, defer-max, exp2,
// __syncthreads, depth-1 reg prefetch).
// ---------------------------------------------------------------------------
__global__ __launch_bounds__(256) void attn_fwd(
    const bf16* __restrict__ q, const bf16* __restrict__ k,
    const bf16* __restrict__ v, bf16* __restrict__ o)
{
    constexpr int LS = 72;
    constexpr float LOG2E = 1.44269504088896340736f;
    __shared__ bf16 Ks[2][64 * LS];   // [buf][key][d]
    __shared__ bf16 Vt[2][64 * LS];   // [buf][d][key]

    const int tid  = threadIdx.x;
    const int lane = tid & 63;
    const int wave = tid >> 6;
    const int l31  = lane & 31;
    const int hi   = lane >> 5;

    // XCD-locality swizzle: all 8 strip-blocks of one bh on ONE XCD.
    // l%8 -> XCD (round-robin dispatch); force bh%8 == l%8.
    const int l   = blockIdx.x;          // 0..511
    const int xcd = l & 7;
    const int jj  = l >> 3;              // 0..63
    const int bh  = ((jj & 7) << 3) | xcd;
    const int p   = jj >> 3;             // 0..7
    const int b   = bh >> 4;
    const int h   = bh & 15;

    const size_t basek = (size_t)b * N_ * E_ + (size_t)h * D_;

    // staging addressing
    const int key0 = tid >> 3;        // 0..31
    const int key1 = key0 + 32;
    const int ck   = (tid & 7) * 8;
    const int kp   = tid & 31;
    const int cv   = (tid >> 5) * 8;

#pragma unroll
    for (int ph = 0; ph < 2; ph++) {
        const int xb = ph == 0 ? (15 - p) : p;
        const int q0 = xb * 128;
        const int nt = 2 * xb + 2;    // key tiles 0..nt-1 (keys 0..q0+127)

        // Q as B-operand of 32x32x16: B[k=hi*8+e][col=qrow=l31], kc selects
        // which 16 of D=64. Pre-scaled by 0.125 (exact in bf16).
        bf16x8 qB[4];
        {
            const size_t qoff =
                ((size_t)b * N_ + q0 + wave * 32 + l31) * E_ + h * D_ + hi * 8;
#pragma unroll
            for (int kc = 0; kc < 4; kc++) {
                qB[kc] = *(const bf16x8*)&q[qoff + kc * 16];
#pragma unroll
                for (int e = 0; e < 8; e++)
                    qB[kc][e] = (__bf16)((float)qB[kc][e] * 0.125f);
            }
        }

        float m_i = -1e30f;
        float l_i = 0.0f;
        f32x16 o_acc[2];              // O^T C-layout: col=qrow, row=d half
#pragma unroll
        for (int rg = 0; rg < 16; rg++) { o_acc[0][rg] = 0.0f; o_acc[1][rg] = 0.0f; }

        // ---- prologue: tile 0 -> buf0; issue loads for tile 1 ----
        bf16x8 kp0, kp1, vp0, vp1;
        kp0 = *(const bf16x8*)&k[basek + (size_t)key0 * E_ + ck];
        kp1 = *(const bf16x8*)&k[basek + (size_t)key1 * E_ + ck];
        vp0 = *(const bf16x8*)&v[basek + (size_t)(2 * kp) * E_ + cv];
        vp1 = *(const bf16x8*)&v[basek + (size_t)(2 * kp + 1) * E_ + cv];
        // (prior phase ended with a barrier -> buffers free)
        *(bf16x8*)&Ks[0][key0 * LS + ck] = kp0;
        *(bf16x8*)&Ks[0][key1 * LS + ck] = kp1;
#pragma unroll
        for (int e = 0; e < 8; e++) {
            union { __bf16 hh[2]; uint32_t u; } pk;
            pk.hh[0] = vp0[e]; pk.hh[1] = vp1[e];
            *(uint32_t*)&Vt[0][(cv + e) * LS + 2 * kp] = pk.u;
        }
        {
            const size_t j1 = 64;     // tile 1 (nt >= 2 always)
            kp0 = *(const bf16x8*)&k[basek + (j1 + key0) * E_ + ck];
            kp1 = *(const bf16x8*)&k[basek + (j1 + key1) * E_ + ck];
            vp0 = *(const bf16x8*)&v[basek + (j1 + 2 * kp) * E_ + cv];
            vp1 = *(const bf16x8*)&v[basek + (j1 + 2 * kp + 1) * E_ + cv];
        }
        __syncthreads();              // buf0 visible to all waves

        for (int t = 0; t < nt; t++) {
            const int cur = t & 1;

            // ---- commit tile t+1 (regs loaded one tile ago) to other buf ----
            if (t + 1 < nt) {
                *(bf16x8*)&Ks[cur ^ 1][key0 * LS + ck] = kp0;
                *(bf16x8*)&Ks[cur ^ 1][key1 * LS + ck] = kp1;
#pragma unroll
                for (int e = 0; e < 8; e++) {
                    union { __bf16 hh[2]; uint32_t u; } pk;
                    pk.hh[0] = vp0[e]; pk.hh[1] = vp1[e];
                    *(uint32_t*)&Vt[cur ^ 1][(cv + e) * LS + 2 * kp] = pk.u;
                }
            }
            // ---- issue loads for tile t+2 (AFTER commit, so commit's vmcnt
            //      wait doesn't include them) ----
            if (t + 2 < nt) {
                const size_t j2 = (size_t)(t + 2) * 64;
                kp0 = *(const bf16x8*)&k[basek + (j2 + key0) * E_ + ck];
                kp1 = *(const bf16x8*)&k[basek + (j2 + key1) * E_ + ck];
                vp0 = *(const bf16x8*)&v[basek + (j2 + 2 * kp) * E_ + cv];
                vp1 = *(const bf16x8*)&v[basek + (j2 + 2 * kp + 1) * E_ + cv];
            }

            // ---- S^T[key][qrow] = K·(scaled Q)^T : 8 MFMA 32x32x16 ----
            f32x16 sf[2];
#pragma unroll
            for (int rg = 0; rg < 16; rg++) { sf[0][rg] = 0.0f; sf[1][rg] = 0.0f; }
#pragma unroll
            for (int kc = 0; kc < 4; kc++) {
                bf16x8 ka0 = *(const bf16x8*)&Ks[cur][l31 * LS + kc * 16 + hi * 8];
                bf16x8 ka1 = *(const bf16x8*)&Ks[cur][(32 + l31) * LS + kc * 16 + hi * 8];
                sf[0] = __builtin_amdgcn_mfma_f32_32x32x16_bf16(ka0, qB[kc], sf[0], 0, 0, 0);
                sf[1] = __builtin_amdgcn_mfma_f32_32x32x16_bf16(ka1, qB[kc], sf[1], 0, 0, 0);
            }

            // ---- causal mask (only last 2 tiles of the phase) ----
            // key = mt*32 + (rg&3) + 8*(rg>>2) + 4*hi ; qrow = l31
            if (t >= nt - 2) {
                const int qgl   = q0 + wave * 32 + l31;
                const int kbase = t * 64 + 4 * hi;
#pragma unroll
                for (int mt = 0; mt < 2; mt++)
#pragma unroll
                    for (int rg = 0; rg < 16; rg++) {
                        const int kgl = kbase + mt * 32 + (rg & 3) + 8 * (rg >> 2);
                        if (kgl > qgl) sf[mt][rg] = -1e30f;
                    }
            }

            // ---- online softmax: each lane owns half its q-row; partner
            //      lane (l^32) owns the other half ----
            float mhalf[8];
#pragma unroll
            for (int i = 0; i < 8; i++)
                mhalf[i] = fmaxf(fmaxf(sf[0][2 * i], sf[0][2 * i + 1]),
                                 fmaxf(sf[1][2 * i], sf[1][2 * i + 1]));
            float mx = fmaxf(fmaxf(fmaxf(mhalf[0], mhalf[1]), fmaxf(mhalf[2], mhalf[3])),
                             fmaxf(fmaxf(mhalf[4], mhalf[5]), fmaxf(mhalf[6], mhalf[7])));
            mx = fmaxf(mx, __shfl_xor(mx, 32));

            // defer-max (THR=8): rescale only when the running max really grew
            if (!__all(mx <= m_i + 8.0f)) {
                const float m_new = fmaxf(m_i, mx);
                const float al = exp2f((m_i - m_new) * LOG2E);
                l_i *= al;
#pragma unroll
                for (int mo = 0; mo < 2; mo++)
#pragma unroll
                    for (int rg = 0; rg < 16; rg++) o_acc[mo][rg] *= al;
                m_i = m_new;
            }

            const float m2 = m_i * LOG2E;
#pragma unroll
            for (int mt = 0; mt < 2; mt++)
#pragma unroll
                for (int rg = 0; rg < 16; rg++)
                    sf[mt][rg] = exp2f(__builtin_fmaf(sf[mt][rg], LOG2E, -m2));

            float ls = 0.0f;
#pragma unroll
            for (int mt = 0; mt < 2; mt++) {
                const float a0 = (sf[mt][0] + sf[mt][1]) + (sf[mt][2] + sf[mt][3]);
                const float a1 = (sf[mt][4] + sf[mt][5]) + (sf[mt][6] + sf[mt][7]);
                const float a2 = (sf[mt][8] + sf[mt][9]) + (sf[mt][10] + sf[mt][11]);
                const float a3 = (sf[mt][12] + sf[mt][13]) + (sf[mt][14] + sf[mt][15]);
                ls += (a0 + a1) + (a2 + a3);
            }
            ls += __shfl_xor(ls, 32);
            l_i += ls;

            // ---- pack P to bf16 pair-words (v_cvt_pk_bf16_f32) ----
            uint32_t w[2][8];
#pragma unroll
            for (int mt = 0; mt < 2; mt++)
#pragma unroll
                for (int i = 0; i < 8; i++) {
                    union { __bf16 hh[2]; uint32_t u; } pk;
                    pk.hh[0] = (__bf16)sf[mt][2 * i];
                    pk.hh[1] = (__bf16)sf[mt][2 * i + 1];
                    w[mt][i] = pk.u;
                }

            // ---- O^T += V^T · P^T : PV B-frags via permlane32_swap ----
            // r1 = swap(w[c], w[c+2]) -> m0 = r1[0], m2 = r1[1] (both halves)
            // r2 = swap(w[c+1], w[c+3]) -> m1 = r2[0], m3 = r2[1]
#pragma unroll
            for (int ks = 0; ks < 4; ks++) {
                const int c  = 4 * (ks & 1);
                const int mt = ks >> 1;
                u32x2 r1 = __builtin_amdgcn_permlane32_swap(
                    w[mt][c + 0], w[mt][c + 2], false, false);
                u32x2 r2 = __builtin_amdgcn_permlane32_swap(
                    w[mt][c + 1], w[mt][c + 3], false, false);
                union { uint32_t u[4]; bf16x8 v8; } pbu;
                pbu.u[0] = r1[0]; pbu.u[1] = r2[0];
                pbu.u[2] = r1[1]; pbu.u[3] = r2[1];
#pragma unroll
                for (int mo = 0; mo < 2; mo++) {
                    bf16x8 va = *(const bf16x8*)
                        &Vt[cur][(mo * 32 + l31) * LS + ks * 16 + hi * 8];
                    o_acc[mo] = __builtin_amdgcn_mfma_f32_32x32x16_bf16(
                        va, pbu.v8, o_acc[mo], 0, 0, 0);
                }
            }

            __syncthreads();   // buf[cur] free for next commit; buf[cur^1] visible
        }

        // ---- normalize + store (O^T: col=qrow=l31, row=d) ----
        {
            const float invl = 1.0f / l_i;
            const size_t orow =
                ((size_t)b * N_ + q0 + wave * 32 + l31) * E_ + h * D_;
#pragma unroll
            for (int mo = 0; mo < 2; mo++)
#pragma unroll
                for (int g = 0; g < 4; g++) {
                    union { __bf16 hh[4]; uint2 u2; } pk;
#pragma unroll
                    for (int j = 0; j < 4; j++)
                        pk.hh[j] = (__bf16)(o_acc[mo][4 * g + j] * invl);
                    *(uint2*)&o[orow + mo * 32 + 8 * g + 4 * hi] = pk.u2;
                }
        }
    }
}

// ---------------------------------------------------------------------------
// Inputs: xq, xk, xv, attn_mask, Wq, Wk, Wv, Wo, bo (all fp32; mask structural)
// ws (big): q|k|v|ao (bf16 8.4M each) | Wb (4x1M) | xb0..2 (8.4M each) =126 MB
// ws (small fallback): first 75.5 MB only; proj GEMM stages fp32 A manually.
// ---------------------------------------------------------------------------
extern "C" void kernel_launch(void* const* d_in, const int* in_sizes, int n_in,
                              void* d_out, int out_size, void* d_ws, size_t ws_size,
                              hipStream_t stream) {
    const float* xq = (const float*)d_in[0];
    const float* xk = (const float*)d_in[1];
    const float* xv = (const float*)d_in[2];
    const float* Wq = (const float*)d_in[4];
    const float* Wk = (const float*)d_in[5];
    const float* Wv = (const float*)d_in[6];
    const float* Wo = (const float*)d_in[7];
    const float* bo = (const float*)d_in[8];
    float* out = (float*)d_out;

    const size_t elems = (size_t)B_ * N_ * E_;   // 8388608
    const size_t wel   = (size_t)E_ * E_;        // 1048576
    bf16* q   = (bf16*)d_ws;
    bf16* kk  = q + elems;
    bf16* vv  = kk + elems;
    bf16* ao  = vv + elems;
    bf16* Wb  = ao + elems;
    bf16* xb0 = Wb + 4 * wel;
    bf16* xb1 = xb0 + elems;
    bf16* xb2 = xb1 + elems;

    const size_t need_big = (7 * elems + 4 * wel) * 2;
    const bool big = ws_size >= need_big;

    dim3 blk(256);
    if (big) {
        cvt_all<<<dim3(14336), blk, 0, stream>>>(
            Wq, Wk, Wv, Wo, Wb, xq, xk, xv, xb0, xb1, xb2);
    } else {
        cvt_all<<<dim3(2048), blk, 0, stream>>>(
            Wq, Wk, Wv, Wo, Wb, nullptr, nullptr, nullptr,
            nullptr, nullptr, nullptr);
    }

    GemmB proj;
    if (big) { proj.A[0] = xb0; proj.A[1] = xb1; proj.A[2] = xb2; }
    else     { proj.A[0] = xq;  proj.A[1] = xk;  proj.A[2] = xv;  }
    proj.C[0] = q; proj.C[1] = kk; proj.C[2] = vv;
    if (big)
        gemm_bt<bf16, bf16><<<dim3(E_ / 128, (B_ * N_) / 128, 3), blk, 0, stream>>>(
            proj, Wb, nullptr);
    else
        gemm_bt<float, bf16><<<dim3(E_ / 128, (B_ * N_) / 128, 3), blk, 0, stream>>>(
            proj, Wb, nullptr);

    attn_fwd<<<dim3(512), blk, 0, stream>>>(q, kk, vv, ao);

    GemmB fin;
    fin.A[0] = ao; fin.A[1] = ao; fin.A[2] = ao;
    fin.C[0] = out; fin.C[1] = out; fin.C[2] = out;
    gemm_bt<bf16, float><<<dim3(E_ / 128, (B_ * N_) / 128, 1), blk, 0, stream>>>(
        fin, Wb + 3 * wel, bo);
}